// Round 1
// 1255.776 us; speedup vs baseline: 1.1619x; 1.1619x over previous
//
#include <hip/hip_runtime.h>
#include <math.h>

#define BJ 192
#define L 512
#define D 128
#define ROWS (BJ*L)          // 98304
#define TI 128
#define TJ 64

#define COMP(v,i) ((i)==0?(v).x:((i)==1?(v).y:((i)==2?(v).z:(v).w)))

typedef __bf16 bf16x8 __attribute__((ext_vector_type(8)));
typedef float  f32x4  __attribute__((ext_vector_type(4)));

__device__ __forceinline__ unsigned short f2bf(float f) {
    unsigned int u = __float_as_uint(f);
    unsigned int r = (u + 0x7fffu + ((u >> 16) & 1u)) >> 16;   // RNE
    return (unsigned short)r;
}

// ---------------- K1: xn = x / max(norm(x),1e-12) (np-bit-exact) + bf16 copy ----------------
// norm: numpy pairwise_sum 8-scalar-acc stride-8 + tree; __fsqrt_rn; __fdiv_rn. (R7-verified)
__global__ __launch_bounds__(256) void k_normalize(const float* __restrict__ x,
                                                   float* __restrict__ xn,
                                                   unsigned short* __restrict__ xnbf) {
    __shared__ float s_x[64 * 132];
    __shared__ float s_nrm[64];
    int t = threadIdx.x;
    size_t row0 = (size_t)blockIdx.x * 64;

    #pragma unroll
    for (int r = 0; r < 8; ++r) {
        int id = t + 256 * r;
        int row = id >> 5, c4 = (id & 31) << 2;
        *(float4*)&s_x[row * 132 + c4] = *(const float4*)(x + (row0 + row) * D + c4);
    }
    __syncthreads();
    if (t < 64) {
        int row = t;
        const float* p = &s_x[row * 132];
        float r8[8];
        #pragma unroll
        for (int l = 0; l < 8; ++l) r8[l] = 0.0f;
        #pragma unroll 1
        for (int i = 0; i < 16; ++i) {
            #pragma unroll
            for (int l = 0; l < 8; ++l) {
                float v = p[i * 8 + l];
                r8[l] = __fadd_rn(r8[l], __fmul_rn(v, v));
            }
        }
        float s01 = __fadd_rn(r8[0], r8[1]);
        float s23 = __fadd_rn(r8[2], r8[3]);
        float s45 = __fadd_rn(r8[4], r8[5]);
        float s67 = __fadd_rn(r8[6], r8[7]);
        float ss  = __fadd_rn(__fadd_rn(s01, s23), __fadd_rn(s45, s67));
        s_nrm[row] = fmaxf(__fsqrt_rn(ss), 1e-12f);
    }
    __syncthreads();
    {
        int row = t >> 2, seg = t & 3;
        float nrm = s_nrm[row];
        float* outp = xn + (row0 + row) * D + seg * 32;
        unsigned short* outb = xnbf + (row0 + row) * D + seg * 32;
        #pragma unroll
        for (int c = 0; c < 8; ++c) {
            float4 v = *(const float4*)&s_x[row * 132 + seg * 32 + c * 4];
            float4 o;
            o.x = __fdiv_rn(v.x, nrm);
            o.y = __fdiv_rn(v.y, nrm);
            o.z = __fdiv_rn(v.z, nrm);
            o.w = __fdiv_rn(v.w, nrm);
            *(float4*)(outp + c * 4) = o;
            ushort4 ob;
            ob.x = f2bf(o.x); ob.y = f2bf(o.y); ob.z = f2bf(o.z); ob.w = f2bf(o.w);
            *(ushort4*)(outb + c * 4) = ob;
        }
    }
}

// ---------------- K2: bf16-MFMA candidate scores + np-exact f32 rescore + gather-mean ----------
// V2 changes (semantics identical to R7):
//  * tv/tjx/scf/rank arrays fully register-resident: every access compile-time-indexed
//    (rescore c-loop + ranking c2-loop fully unrolled).  R7 had runtime indices -> scratch,
//    which put the scan's tv[15] compare and every insertion swap on a global-memory RTT.
//  * rescore reads xi/xj at 64B-line granularity (g unrolled x4, x2 deep) -> MSHR-merged,
//    kills the ~4x line over-fetch (FETCH 986MB) and exposes ~16 loads of MLP.
//  * exchange LDS stride 32->33 (s_cf/s_ci) and 8->9 (s_win): was a 64-way bank conflict
//    (1.39e7 SQ_LDS_BANK_CONFLICT), now conflict-free.
//  * s_sc stride 65->68 (16B aligned): scan reads float4 (1 ds_read_b128 per 4 scores,
//    pipelined 1 ahead, quad-max reject); scatter writes drop 4-way -> free 2-way.
//  * __launch_bounds__(256,3): grid is exactly 3 blocks/CU; allow VGPRs up to ~168.
__global__ __launch_bounds__(256, 3) void k_topk_agg(const float* __restrict__ x,
                                                     const float* __restrict__ xn,
                                                     const unsigned short* __restrict__ xnbf,
                                                     float* __restrict__ xagg) {
    __shared__ __align__(16) char smem[38400];
    float* s_sc = (float*)smem;            // Phase A: 128*68 floats (34816 B), aliased over Xi/Bj
    float* s_cf = (float*)smem;            // Phase B: 128*33 floats (16896 B)
    int* s_ci   = (int*)(smem + 16896);    // 128*33 ints  (16896 B)
    int* s_win  = (int*)(smem + 33792);    // 128*9 ints   (4608 B)  -> total 38400

    int bj = blockIdx.y;
    int i0 = blockIdx.x * TI;
    int t  = threadIdx.x;
    int w  = t >> 6;            // wave 0..3
    int l  = t & 63;            // lane
    int quad = l >> 4;          // 0..3
    int m16  = l & 15;          // 0..15
    const float* xb  = x  + (size_t)bj * L * D;
    const float* xnb = xn + (size_t)bj * L * D;
    const unsigned short* xfb = xnbf + (size_t)bj * L * D;

    // ---- stage Xi (bf16, swizzled) ----
    #pragma unroll
    for (int r = 0; r < 8; ++r) {
        int id = t + 256 * r;
        int row = id >> 4, c = id & 15;
        uint4 v = *(const uint4*)(xfb + (size_t)(i0 + row) * D + c * 8);
        *(uint4*)(smem + row * 256 + ((c ^ (row & 15)) << 4)) = v;
    }
    __syncthreads();
    // ---- A-frags: wave w owns i-rows [w*32, w*32+32); register-resident for all jt ----
    bf16x8 afr[2][4];
    #pragma unroll
    for (int mt = 0; mt < 2; ++mt)
        #pragma unroll
        for (int s = 0; s < 4; ++s) {
            int row = w * 32 + mt * 16 + m16;
            int c = s * 4 + quad;
            afr[mt][s] = *(const bf16x8*)(smem + row * 256 + ((c ^ m16) << 4));
        }
    __syncthreads();   // Xi region free

    float tv[16]; int tjx[16];
    #pragma unroll
    for (int c = 0; c < 16; ++c) { tv[c] = -3.4e38f; tjx[c] = 0; }

    for (int jt = 0; jt < L / TJ; ++jt) {   // 8 j-tiles of 64
        // stage Bj (bf16, swizzled) into smem[0..16K)
        #pragma unroll
        for (int r = 0; r < 4; ++r) {
            int id = t + 256 * r;
            int row = id >> 4, c = id & 15;
            uint4 v = *(const uint4*)(xfb + (size_t)(jt * TJ + row) * D + c * 8);
            *(uint4*)(smem + row * 256 + ((c ^ (row & 15)) << 4)) = v;
        }
        __syncthreads();
        // MFMA: acc[mt][u] over K-steps
        f32x4 acc[2][4];
        #pragma unroll
        for (int mt = 0; mt < 2; ++mt)
            #pragma unroll
            for (int u = 0; u < 4; ++u) acc[mt][u] = (f32x4){0.f, 0.f, 0.f, 0.f};
        #pragma unroll
        for (int s = 0; s < 4; ++s) {
            bf16x8 bfr[4];
            #pragma unroll
            for (int u = 0; u < 4; ++u) {
                int row = u * 16 + m16;
                int c = s * 4 + quad;
                bfr[u] = *(const bf16x8*)(smem + row * 256 + ((c ^ m16) << 4));
            }
            #pragma unroll
            for (int u = 0; u < 4; ++u)
                #pragma unroll
                for (int mt = 0; mt < 2; ++mt)
                    acc[mt][u] = __builtin_amdgcn_mfma_f32_16x16x32_bf16(
                        afr[mt][s], bfr[u], acc[mt][u], 0, 0, 0);
        }
        __syncthreads();   // Bj consumed; region now s_sc
        // C/D layout: col = lane&15, row = quad*4 + reg  [m89-verified]
        #pragma unroll
        for (int mt = 0; mt < 2; ++mt)
            #pragma unroll
            for (int u = 0; u < 4; ++u)
                #pragma unroll
                for (int reg = 0; reg < 4; ++reg) {
                    int irow = w * 32 + mt * 16 + quad * 4 + reg;
                    s_sc[irow * 68 + u * 16 + m16] = acc[mt][u][reg];
                }
        __syncthreads();
        // scan: row = t&127, stripe q = t>>7 scans 32 cols, ascending j.
        // float4 reads (pipelined one ahead) + quad-max reject; pool update order
        // identical to R7's scalar ascending scan (strict >, earlier j kept on ties).
        {
            int row = t & 127, q = t >> 7;
            const float* bp = &s_sc[row * 68 + q * 32];
            int jbase = jt * TJ + q * 32;
            float4 cur = *(const float4*)bp;
            #pragma unroll 1
            for (int s4 = 0; s4 < 8; ++s4) {
                float4 nxt = cur;
                if (s4 < 7) nxt = *(const float4*)(bp + (s4 + 1) * 4);
                float mx = fmaxf(fmaxf(cur.x, cur.y), fmaxf(cur.z, cur.w));
                if (mx > tv[15]) {
                    #pragma unroll
                    for (int e = 0; e < 4; ++e) {
                        float v = COMP(cur, e);
                        if (v > tv[15]) {
                            tv[15] = v; tjx[15] = jbase + s4 * 4 + e;
                            #pragma unroll
                            for (int p = 15; p > 0; --p) {
                                if (tv[p] > tv[p - 1]) {
                                    float ft = tv[p - 1]; tv[p - 1] = tv[p]; tv[p] = ft;
                                    int   it = tjx[p - 1]; tjx[p - 1] = tjx[p]; tjx[p] = it;
                                }
                            }
                        }
                    }
                }
                cur = nxt;
            }
        }
        __syncthreads();   // scan done before next stage overwrites
    }

    // ---- Phase B: numpy-einsum-SSE-exact f32 rescore of the 32 candidates per row ----
    // Per-candidate add order unchanged: P0..P3 strided lanes, ascending g, mul+add,
    // then pairwise (P0+P1)+(P2+P3). c-loop fully unrolled -> tjx/scf in VGPRs.
    int rowB = t & 127, qB = t >> 7;
    float scf[16];
    {
        const float* xi = xnb + (size_t)(i0 + rowB) * D;
        #pragma unroll
        for (int c = 0; c < 16; ++c) {
            const float* xj = xnb + (size_t)tjx[c] * D;
            float P0 = 0.f, P1 = 0.f, P2 = 0.f, P3 = 0.f;
            #pragma unroll 2
            for (int g4 = 0; g4 < 8; ++g4) {     // one 64B line per stream per iter
                float4 a0 = *(const float4*)(xi + g4 * 16 + 0);
                float4 a1 = *(const float4*)(xi + g4 * 16 + 4);
                float4 a2 = *(const float4*)(xi + g4 * 16 + 8);
                float4 a3 = *(const float4*)(xi + g4 * 16 + 12);
                float4 b0 = *(const float4*)(xj + g4 * 16 + 0);
                float4 b1 = *(const float4*)(xj + g4 * 16 + 4);
                float4 b2 = *(const float4*)(xj + g4 * 16 + 8);
                float4 b3 = *(const float4*)(xj + g4 * 16 + 12);
                P0 = __fadd_rn(P0, __fmul_rn(a0.x, b0.x));
                P1 = __fadd_rn(P1, __fmul_rn(a0.y, b0.y));
                P2 = __fadd_rn(P2, __fmul_rn(a0.z, b0.z));
                P3 = __fadd_rn(P3, __fmul_rn(a0.w, b0.w));
                P0 = __fadd_rn(P0, __fmul_rn(a1.x, b1.x));
                P1 = __fadd_rn(P1, __fmul_rn(a1.y, b1.y));
                P2 = __fadd_rn(P2, __fmul_rn(a1.z, b1.z));
                P3 = __fadd_rn(P3, __fmul_rn(a1.w, b1.w));
                P0 = __fadd_rn(P0, __fmul_rn(a2.x, b2.x));
                P1 = __fadd_rn(P1, __fmul_rn(a2.y, b2.y));
                P2 = __fadd_rn(P2, __fmul_rn(a2.z, b2.z));
                P3 = __fadd_rn(P3, __fmul_rn(a2.w, b2.w));
                P0 = __fadd_rn(P0, __fmul_rn(a3.x, b3.x));
                P1 = __fadd_rn(P1, __fmul_rn(a3.y, b3.y));
                P2 = __fadd_rn(P2, __fmul_rn(a3.z, b3.z));
                P3 = __fadd_rn(P3, __fmul_rn(a3.w, b3.w));
            }
            float sc = __fadd_rn(__fadd_rn(P0, P1), __fadd_rn(P2, P3));
            scf[c] = sc;
            s_cf[rowB * 33 + qB * 16 + c] = sc;
            s_ci[rowB * 33 + qB * 16 + c] = tjx[c];
        }
    }
    __syncthreads();
    // rank my 16 candidates among all 32 (value desc, tie -> lower index)
    {
        int rank[16];
        #pragma unroll
        for (int c = 0; c < 16; ++c) rank[c] = 0;
        #pragma unroll
        for (int c2 = 0; c2 < 16; ++c2) {
            float v2 = scf[c2]; int i2 = tjx[c2];
            #pragma unroll
            for (int c = 0; c < 16; ++c) {
                bool better = (v2 > scf[c]) || (v2 == scf[c] && i2 < tjx[c]);
                rank[c] += better ? 1 : 0;
            }
        }
        int ob = rowB * 33 + (1 - qB) * 16;
        #pragma unroll 1
        for (int o = 0; o < 16; ++o) {
            float vo = s_cf[ob + o]; int io = s_ci[ob + o];
            #pragma unroll
            for (int c = 0; c < 16; ++c) {
                bool better = (vo > scf[c]) || (vo == scf[c] && io < tjx[c]);
                rank[c] += better ? 1 : 0;
            }
        }
        #pragma unroll
        for (int c = 0; c < 16; ++c)
            if (rank[c] < 8) s_win[rowB * 9 + rank[c]] = tjx[c];
    }
    __syncthreads();
    // gather-mean of raw x rows -> x_agg; pairwise tree-of-8, then *0.125 (exact)
    {
        int row = t >> 1, half = t & 1;
        int idxs[8];
        #pragma unroll
        for (int w8 = 0; w8 < 8; ++w8) idxs[w8] = s_win[row * 9 + w8];
        const float* bb  = xb + half * 64;
        float* outp = xagg + ((size_t)(bj * L + i0 + row)) * D + half * 64;
        #pragma unroll
        for (int c = 0; c < 16; ++c) {
            float4 v[8];
            #pragma unroll
            for (int w8 = 0; w8 < 8; ++w8)
                v[w8] = *(const float4*)(bb + idxs[w8] * D + c * 4);
            float4 a4;
            a4.x = __fadd_rn(__fadd_rn(__fadd_rn(v[0].x, v[1].x), __fadd_rn(v[2].x, v[3].x)),
                             __fadd_rn(__fadd_rn(v[4].x, v[5].x), __fadd_rn(v[6].x, v[7].x)));
            a4.y = __fadd_rn(__fadd_rn(__fadd_rn(v[0].y, v[1].y), __fadd_rn(v[2].y, v[3].y)),
                             __fadd_rn(__fadd_rn(v[4].y, v[5].y), __fadd_rn(v[6].y, v[7].y)));
            a4.z = __fadd_rn(__fadd_rn(__fadd_rn(v[0].z, v[1].z), __fadd_rn(v[2].z, v[3].z)),
                             __fadd_rn(__fadd_rn(v[4].z, v[5].z), __fadd_rn(v[6].z, v[7].z)));
            a4.w = __fadd_rn(__fadd_rn(__fadd_rn(v[0].w, v[1].w), __fadd_rn(v[2].w, v[3].w)),
                             __fadd_rn(__fadd_rn(v[4].w, v[5].w), __fadd_rn(v[6].w, v[7].w)));
            a4.x *= 0.125f; a4.y *= 0.125f; a4.z *= 0.125f; a4.w *= 0.125f;
            *(float4*)(outp + c * 4) = a4;
        }
    }
}

// ---------------- K3: h = x_agg @ W + b, LayerNorm -> hn (in-place over x_agg ws) ----------------
__global__ __launch_bounds__(256) void k_gemm1_ln(float* __restrict__ ws0,
                                                  const float* __restrict__ W,
                                                  const float* __restrict__ bvec,
                                                  const float* __restrict__ gamma,
                                                  const float* __restrict__ beta) {
    __shared__ float s_a[64 * 132];
    __shared__ float s_red[640];
    int t = threadIdx.x;
    size_t row0 = (size_t)blockIdx.x * 64;

    #pragma unroll
    for (int r = 0; r < 8; ++r) {
        int id = t + 256 * r;
        int row = id >> 5, c4 = (id & 31) << 2;
        *(float4*)&s_a[row * 132 + c4] = *(const float4*)(ws0 + (row0 + row) * D + c4);
    }
    __syncthreads();

    int mg = t >> 4, ng = t & 15;
    float acc[4][8];
    #pragma unroll
    for (int s = 0; s < 4; ++s)
        #pragma unroll
        for (int n = 0; n < 8; ++n) acc[s][n] = 0.0f;

    #pragma unroll 4
    for (int kc = 0; kc < 32; ++kc) {
        float4 a[4];
        #pragma unroll
        for (int s = 0; s < 4; ++s) a[s] = *(const float4*)&s_a[(mg + 16 * s) * 132 + kc * 4];
        #pragma unroll
        for (int i = 0; i < 4; ++i) {
            int k = kc * 4 + i;
            float4 bA = *(const float4*)(W + k * D + ng * 8);
            float4 bB = *(const float4*)(W + k * D + ng * 8 + 4);
            #pragma unroll
            for (int s = 0; s < 4; ++s) {
                float av = COMP(a[s], i);
                acc[s][0] = fmaf(av, bA.x, acc[s][0]);
                acc[s][1] = fmaf(av, bA.y, acc[s][1]);
                acc[s][2] = fmaf(av, bA.z, acc[s][2]);
                acc[s][3] = fmaf(av, bA.w, acc[s][3]);
                acc[s][4] = fmaf(av, bB.x, acc[s][4]);
                acc[s][5] = fmaf(av, bB.y, acc[s][5]);
                acc[s][6] = fmaf(av, bB.z, acc[s][6]);
                acc[s][7] = fmaf(av, bB.w, acc[s][7]);
            }
        }
    }
    __syncthreads();
    {
        float4 bA = *(const float4*)(bvec + ng * 8);
        float4 bB = *(const float4*)(bvec + ng * 8 + 4);
        #pragma unroll
        for (int s = 0; s < 4; ++s) {
            int row = mg + 16 * s;
            float4 h0 = make_float4(acc[s][0] + bA.x, acc[s][1] + bA.y,
                                    acc[s][2] + bA.z, acc[s][3] + bA.w);
            float4 h1 = make_float4(acc[s][4] + bB.x, acc[s][5] + bB.y,
                                    acc[s][6] + bB.z, acc[s][7] + bB.w);
            *(float4*)&s_a[row * 132 + ng * 8]     = h0;
            *(float4*)&s_a[row * 132 + ng * 8 + 4] = h1;
        }
    }
    __syncthreads();
    {
        int row = t & 63, q = t >> 6;
        float sm = 0.f, ssq = 0.f;
        #pragma unroll
        for (int c4 = 0; c4 < 8; ++c4) {
            float4 h = *(const float4*)&s_a[row * 132 + q * 32 + c4 * 4];
            sm += h.x + h.y + h.z + h.w;
            ssq = fmaf(h.x, h.x, ssq); ssq = fmaf(h.y, h.y, ssq);
            ssq = fmaf(h.z, h.z, ssq); ssq = fmaf(h.w, h.w, ssq);
        }
        s_red[row * 4 + q] = sm;
        s_red[256 + row * 4 + q] = ssq;
    }
    __syncthreads();
    if (t < 64) {
        float sm  = s_red[t * 4] + s_red[t * 4 + 1] + s_red[t * 4 + 2] + s_red[t * 4 + 3];
        float ssq = s_red[256 + t * 4] + s_red[256 + t * 4 + 1] +
                    s_red[256 + t * 4 + 2] + s_red[256 + t * 4 + 3];
        float mu  = sm * (1.0f / 128.0f);
        float var = ssq * (1.0f / 128.0f) - mu * mu;
        s_red[512 + t] = mu;
        s_red[576 + t] = 1.0f / sqrtf(var + 1e-5f);
    }
    __syncthreads();
    {
        int row = t & 63, q = t >> 6;
        float mu = s_red[512 + row], rs = s_red[576 + row];
        float* outp = ws0 + (row0 + row) * D + q * 32;
        #pragma unroll
        for (int c4 = 0; c4 < 8; ++c4) {
            float4 h  = *(const float4*)&s_a[row * 132 + q * 32 + c4 * 4];
            float4 g  = *(const float4*)(gamma + q * 32 + c4 * 4);
            float4 bt = *(const float4*)(beta  + q * 32 + c4 * 4);
            float4 o;
            o.x = fmaf((h.x - mu) * rs, g.x, bt.x);
            o.y = fmaf((h.y - mu) * rs, g.y, bt.y);
            o.z = fmaf((h.z - mu) * rs, g.z, bt.z);
            o.w = fmaf((h.w - mu) * rs, g.w, bt.w);
            *(float4*)(outp + c4 * 4) = o;
        }
    }
}

// ---------------- K4: out = relu(hn@W1+b1)@W2 + b2 ----------------
__global__ __launch_bounds__(256) void k_mlp(const float* __restrict__ hn,
                                             const float* __restrict__ W1,
                                             const float* __restrict__ b1,
                                             const float* __restrict__ W2,
                                             const float* __restrict__ b2,
                                             float* __restrict__ out) {
    __shared__ float s_h[32 * 132];
    __shared__ float s_t[32 * 132];
    int t = threadIdx.x;
    size_t row0 = (size_t)blockIdx.x * 32;

    #pragma unroll
    for (int r = 0; r < 4; ++r) {
        int id = t + 256 * r;
        int row = id >> 5, c4 = (id & 31) << 2;
        *(float4*)&s_h[row * 132 + c4] = *(const float4*)(hn + (row0 + row) * D + c4);
    }
    __syncthreads();

    int mg = t >> 5, ng = t & 31;
    float oacc[4][4];
    #pragma unroll
    for (int s = 0; s < 4; ++s)
        #pragma unroll
        for (int c = 0; c < 4; ++c) oacc[s][c] = 0.0f;

    for (int half = 0; half < 2; ++half) {
        float tacc[4][4];
        #pragma unroll
        for (int s = 0; s < 4; ++s)
            #pragma unroll
            for (int c = 0; c < 4; ++c) tacc[s][c] = 0.0f;
        #pragma unroll 4
        for (int kc = 0; kc < 32; ++kc) {
            float4 a[4];
            #pragma unroll
            for (int s = 0; s < 4; ++s) a[s] = *(const float4*)&s_h[(mg + 8 * s) * 132 + kc * 4];
            #pragma unroll
            for (int i = 0; i < 4; ++i) {
                float4 b = *(const float4*)(W1 + (kc * 4 + i) * 256 + half * 128 + ng * 4);
                #pragma unroll
                for (int s = 0; s < 4; ++s) {
                    float av = COMP(a[s], i);
                    tacc[s][0] = fmaf(av, b.x, tacc[s][0]);
                    tacc[s][1] = fmaf(av, b.y, tacc[s][1]);
                    tacc[s][2] = fmaf(av, b.z, tacc[s][2]);
                    tacc[s][3] = fmaf(av, b.w, tacc[s][3]);
                }
            }
        }
        float4 bb1 = *(const float4*)(b1 + half * 128 + ng * 4);
        #pragma unroll
        for (int s = 0; s < 4; ++s) {
            tacc[s][0] = fmaxf(tacc[s][0] + bb1.x, 0.0f);
            tacc[s][1] = fmaxf(tacc[s][1] + bb1.y, 0.0f);
            tacc[s][2] = fmaxf(tacc[s][2] + bb1.z, 0.0f);
            tacc[s][3] = fmaxf(tacc[s][3] + bb1.w, 0.0f);
        }
        __syncthreads();
        #pragma unroll
        for (int s = 0; s < 4; ++s)
            *(float4*)&s_t[(mg + 8 * s) * 132 + ng * 4] =
                make_float4(tacc[s][0], tacc[s][1], tacc[s][2], tacc[s][3]);
        __syncthreads();
        #pragma unroll 4
        for (int kc = 0; kc < 32; ++kc) {
            float4 a[4];
            #pragma unroll
            for (int s = 0; s < 4; ++s) a[s] = *(const float4*)&s_t[(mg + 8 * s) * 132 + kc * 4];
            #pragma unroll
            for (int i = 0; i < 4; ++i) {
                float4 b = *(const float4*)(W2 + (half * 128 + kc * 4 + i) * 128 + ng * 4);
                #pragma unroll
                for (int s = 0; s < 4; ++s) {
                    float av = COMP(a[s], i);
                    oacc[s][0] = fmaf(av, b.x, oacc[s][0]);
                    oacc[s][1] = fmaf(av, b.y, oacc[s][1]);
                    oacc[s][2] = fmaf(av, b.z, oacc[s][2]);
                    oacc[s][3] = fmaf(av, b.w, oacc[s][3]);
                }
            }
        }
    }
    float4 bb2 = *(const float4*)(b2 + ng * 4);
    #pragma unroll
    for (int s = 0; s < 4; ++s) {
        float4 o = make_float4(oacc[s][0] + bb2.x, oacc[s][1] + bb2.y,
                               oacc[s][2] + bb2.z, oacc[s][3] + bb2.w);
        *(float4*)(out + (row0 + mg + 8 * s) * D + ng * 4) = o;
    }
}

extern "C" void kernel_launch(void* const* d_in, const int* in_sizes, int n_in,
                              void* d_out, int out_size, void* d_ws, size_t ws_size,
                              hipStream_t stream) {
    const float* x     = (const float*)d_in[0];
    const float* W     = (const float*)d_in[1];
    const float* b     = (const float*)d_in[2];
    const float* W1    = (const float*)d_in[3];
    const float* b1    = (const float*)d_in[4];
    const float* W2    = (const float*)d_in[5];
    const float* b2    = (const float*)d_in[6];
    const float* gamma = (const float*)d_in[7];
    const float* beta  = (const float*)d_in[8];

    float* ws   = (float*)d_ws;
    float* xagg = ws;                                   // ROWS*D f32; becomes hn after K3
    float* xn   = ws + (size_t)ROWS * D;                // ROWS*D f32 (np-bit-exact xn)
    unsigned short* xnbf = (unsigned short*)(ws + 2 * (size_t)ROWS * D);  // ROWS*D bf16

    hipLaunchKernelGGL(k_normalize, dim3(ROWS / 64), dim3(256), 0, stream, x, xn, xnbf);
    hipLaunchKernelGGL(k_topk_agg,  dim3(4, BJ),     dim3(256), 0, stream, x, xn, xnbf, xagg);
    hipLaunchKernelGGL(k_gemm1_ln,  dim3(ROWS / 64), dim3(256), 0, stream, xagg, W, b, gamma, beta);
    hipLaunchKernelGGL(k_mlp,       dim3(ROWS / 32), dim3(256), 0, stream, xagg, W1, b1, W2, b2,
                       (float*)d_out);
}

// Round 2
// 1195.776 us; speedup vs baseline: 1.2202x; 1.0502x over previous
//
#include <hip/hip_runtime.h>
#include <math.h>

#define BJ 192
#define L 512
#define D 128
#define ROWS (BJ*L)          // 98304
#define TI 128
#define TJ 64

#define COMP(v,i) ((i)==0?(v).x:((i)==1?(v).y:((i)==2?(v).z:(v).w)))

typedef __bf16 bf16x8 __attribute__((ext_vector_type(8)));
typedef float  f32x4  __attribute__((ext_vector_type(4)));

__device__ __forceinline__ unsigned short f2bf(float f) {
    unsigned int u = __float_as_uint(f);
    unsigned int r = (u + 0x7fffu + ((u >> 16) & 1u)) >> 16;   // RNE
    return (unsigned short)r;
}

// ---------------- K1: xn = x / max(norm(x),1e-12) (np-bit-exact) + bf16 copy ----------------
__global__ __launch_bounds__(256) void k_normalize(const float* __restrict__ x,
                                                   float* __restrict__ xn,
                                                   unsigned short* __restrict__ xnbf) {
    __shared__ float s_x[64 * 132];
    __shared__ float s_nrm[64];
    int t = threadIdx.x;
    size_t row0 = (size_t)blockIdx.x * 64;

    #pragma unroll
    for (int r = 0; r < 8; ++r) {
        int id = t + 256 * r;
        int row = id >> 5, c4 = (id & 31) << 2;
        *(float4*)&s_x[row * 132 + c4] = *(const float4*)(x + (row0 + row) * D + c4);
    }
    __syncthreads();
    if (t < 64) {
        int row = t;
        const float* p = &s_x[row * 132];
        float r8[8];
        #pragma unroll
        for (int l = 0; l < 8; ++l) r8[l] = 0.0f;
        #pragma unroll 1
        for (int i = 0; i < 16; ++i) {
            #pragma unroll
            for (int l = 0; l < 8; ++l) {
                float v = p[i * 8 + l];
                r8[l] = __fadd_rn(r8[l], __fmul_rn(v, v));
            }
        }
        float s01 = __fadd_rn(r8[0], r8[1]);
        float s23 = __fadd_rn(r8[2], r8[3]);
        float s45 = __fadd_rn(r8[4], r8[5]);
        float s67 = __fadd_rn(r8[6], r8[7]);
        float ss  = __fadd_rn(__fadd_rn(s01, s23), __fadd_rn(s45, s67));
        s_nrm[row] = fmaxf(__fsqrt_rn(ss), 1e-12f);
    }
    __syncthreads();
    {
        int row = t >> 2, seg = t & 3;
        float nrm = s_nrm[row];
        float* outp = xn + (row0 + row) * D + seg * 32;
        unsigned short* outb = xnbf + (row0 + row) * D + seg * 32;
        #pragma unroll
        for (int c = 0; c < 8; ++c) {
            float4 v = *(const float4*)&s_x[row * 132 + seg * 32 + c * 4];
            float4 o;
            o.x = __fdiv_rn(v.x, nrm);
            o.y = __fdiv_rn(v.y, nrm);
            o.z = __fdiv_rn(v.z, nrm);
            o.w = __fdiv_rn(v.w, nrm);
            *(float4*)(outp + c * 4) = o;
            ushort4 ob;
            ob.x = f2bf(o.x); ob.y = f2bf(o.y); ob.z = f2bf(o.z); ob.w = f2bf(o.w);
            *(ushort4*)(outb + c * 4) = ob;
        }
    }
}

// ---------------- K2a: bf16-MFMA candidate scores -> 32 candidate indices per row ------------
// Phase A of the old fused kernel, unchanged semantics; dumps tjx[16] per (row,stripe) as u16.
// Ranking/rescore moved to K2b (pure function of the 32 (exact-score, idx) pairs).
__global__ __launch_bounds__(256, 3) void k_topk_cand(const unsigned short* __restrict__ xnbf,
                                                      unsigned short* __restrict__ cand) {
    __shared__ __align__(16) char smem[34816];
    float* s_sc = (float*)smem;            // 128*68 floats, aliased over Xi/Bj staging

    int bj = blockIdx.y;
    int i0 = blockIdx.x * TI;
    int t  = threadIdx.x;
    int w  = t >> 6;            // wave 0..3
    int l  = t & 63;            // lane
    int quad = l >> 4;          // 0..3
    int m16  = l & 15;          // 0..15
    const unsigned short* xfb = xnbf + (size_t)bj * L * D;

    // ---- stage Xi (bf16, swizzled) ----
    #pragma unroll
    for (int r = 0; r < 8; ++r) {
        int id = t + 256 * r;
        int row = id >> 4, c = id & 15;
        uint4 v = *(const uint4*)(xfb + (size_t)(i0 + row) * D + c * 8);
        *(uint4*)(smem + row * 256 + ((c ^ (row & 15)) << 4)) = v;
    }
    __syncthreads();
    // ---- A-frags: wave w owns i-rows [w*32, w*32+32); register-resident for all jt ----
    bf16x8 afr[2][4];
    #pragma unroll
    for (int mt = 0; mt < 2; ++mt)
        #pragma unroll
        for (int s = 0; s < 4; ++s) {
            int row = w * 32 + mt * 16 + m16;
            int c = s * 4 + quad;
            afr[mt][s] = *(const bf16x8*)(smem + row * 256 + ((c ^ m16) << 4));
        }
    __syncthreads();   // Xi region free

    float tv[16]; int tjx[16];
    #pragma unroll
    for (int c = 0; c < 16; ++c) { tv[c] = -3.4e38f; tjx[c] = 0; }

    for (int jt = 0; jt < L / TJ; ++jt) {   // 8 j-tiles of 64
        // stage Bj (bf16, swizzled)
        #pragma unroll
        for (int r = 0; r < 4; ++r) {
            int id = t + 256 * r;
            int row = id >> 4, c = id & 15;
            uint4 v = *(const uint4*)(xfb + (size_t)(jt * TJ + row) * D + c * 8);
            *(uint4*)(smem + row * 256 + ((c ^ (row & 15)) << 4)) = v;
        }
        __syncthreads();
        f32x4 acc[2][4];
        #pragma unroll
        for (int mt = 0; mt < 2; ++mt)
            #pragma unroll
            for (int u = 0; u < 4; ++u) acc[mt][u] = (f32x4){0.f, 0.f, 0.f, 0.f};
        #pragma unroll
        for (int s = 0; s < 4; ++s) {
            bf16x8 bfr[4];
            #pragma unroll
            for (int u = 0; u < 4; ++u) {
                int row = u * 16 + m16;
                int c = s * 4 + quad;
                bfr[u] = *(const bf16x8*)(smem + row * 256 + ((c ^ m16) << 4));
            }
            #pragma unroll
            for (int u = 0; u < 4; ++u)
                #pragma unroll
                for (int mt = 0; mt < 2; ++mt)
                    acc[mt][u] = __builtin_amdgcn_mfma_f32_16x16x32_bf16(
                        afr[mt][s], bfr[u], acc[mt][u], 0, 0, 0);
        }
        __syncthreads();   // Bj consumed; region now s_sc
        // C/D layout: col = lane&15, row = quad*4 + reg  [m89-verified]
        #pragma unroll
        for (int mt = 0; mt < 2; ++mt)
            #pragma unroll
            for (int u = 0; u < 4; ++u)
                #pragma unroll
                for (int reg = 0; reg < 4; ++reg) {
                    int irow = w * 32 + mt * 16 + quad * 4 + reg;
                    s_sc[irow * 68 + u * 16 + m16] = acc[mt][u][reg];
                }
        __syncthreads();
        // scan: row = t&127, stripe q = t>>7 scans 32 cols, ascending j (pool semantics
        // identical to R7: strict >, earlier j kept on ties).
        {
            int row = t & 127, q = t >> 7;
            const float* bp = &s_sc[row * 68 + q * 32];
            int jbase = jt * TJ + q * 32;
            float4 cur = *(const float4*)bp;
            #pragma unroll 1
            for (int s4 = 0; s4 < 8; ++s4) {
                float4 nxt = cur;
                if (s4 < 7) nxt = *(const float4*)(bp + (s4 + 1) * 4);
                float mx = fmaxf(fmaxf(cur.x, cur.y), fmaxf(cur.z, cur.w));
                if (mx > tv[15]) {
                    #pragma unroll
                    for (int e = 0; e < 4; ++e) {
                        float v = COMP(cur, e);
                        if (v > tv[15]) {
                            tv[15] = v; tjx[15] = jbase + s4 * 4 + e;
                            #pragma unroll
                            for (int p = 15; p > 0; --p) {
                                if (tv[p] > tv[p - 1]) {
                                    float ft = tv[p - 1]; tv[p - 1] = tv[p]; tv[p] = ft;
                                    int   it = tjx[p - 1]; tjx[p - 1] = tjx[p]; tjx[p] = it;
                                }
                            }
                        }
                    }
                }
                cur = nxt;
            }
        }
        __syncthreads();   // scan done before next stage overwrites
    }

    // dump candidates: row-global layout [R*32 + q*16 + c], j fits u16
    {
        int rowB = t & 127, qB = t >> 7;
        unsigned short* cp = cand + ((size_t)(bj * L + i0 + rowB)) * 32 + qB * 16;
        #pragma unroll
        for (int c = 0; c < 16; ++c) cp[c] = (unsigned short)tjx[c];
    }
}

// ---------------- K2b: np-exact f32 rescore + rank + gather-mean, one WAVE per row ----------
// 2 lanes per candidate: even lane runs P0,P1 chains, odd lane P2,P3 (identical serial
// __fadd_rn order); combine fadd(fadd(P0,P1),fadd(P2,P3)) via shfl_xor — bit-exact vs the
// single-thread SSE replica. Rank = pure function of 32 (score,idx) pairs (all j distinct).
// Gather: lane handles elems {2l,2l+1}; tree-of-8 __fadd_rn then *0.125 — unchanged.
// XCD-chunked bijective swizzle (24576 % 8 == 0): each XCD works a contiguous bj range ->
// per-XCD live set ~1 MB << 4 MB L2 (was ~100 MB thrash -> 1.42 GB FETCH).
__global__ __launch_bounds__(256) void k_rescore_agg(const float* __restrict__ x,
                                                     const float* __restrict__ xn,
                                                     const unsigned short* __restrict__ cand,
                                                     float* __restrict__ xagg) {
    __shared__ float s_sc[4][32];
    __shared__ int   s_ix[4][32];
    __shared__ int   s_win[4][8];
    int t  = threadIdx.x;
    int wv = t >> 6, l = t & 63;
    int nwg = ROWS / 4;                       // 24576
    int bid = blockIdx.x;
    int swz = (bid & 7) * (nwg >> 3) + (bid >> 3);
    size_t R = (size_t)swz * 4 + wv;          // global row
    int bj    = (int)(R >> 9);
    int i_loc = (int)(R & 511);
    const float* xnb = xn + (((size_t)bj) << 9) * D;
    const float* xb  = x  + (((size_t)bj) << 9) * D;

    // ---- rescore: candidate c = l>>1, sub-chain pair = l&1 ----
    int c   = l >> 1;
    int sub = l & 1;
    int jc  = (int)cand[R * 32 + c];
    const float* xi = xnb + (size_t)i_loc * D + 2 * sub;
    const float* xj = xnb + (size_t)jc * D + 2 * sub;
    float Pa = 0.f, Pb = 0.f;
    #pragma unroll
    for (int g = 0; g < 32; ++g) {
        float2 a2 = *(const float2*)(xi + g * 4);
        float2 b2 = *(const float2*)(xj + g * 4);
        Pa = __fadd_rn(Pa, __fmul_rn(a2.x, b2.x));
        Pb = __fadd_rn(Pb, __fmul_rn(a2.y, b2.y));
    }
    float s  = __fadd_rn(Pa, Pb);      // even: fadd(P0,P1); odd: fadd(P2,P3)
    float so = __shfl_xor(s, 1);
    if (sub == 0) {
        s_sc[wv][c] = __fadd_rn(s, so);   // fadd(fadd(P0,P1), fadd(P2,P3)) — exact order
        s_ix[wv][c] = jc;
    }
    __syncthreads();

    // ---- rank among all 32 (value desc, tie -> lower index); winners rank<8 in rank order --
    if (l < 32) {
        float v = s_sc[wv][l]; int iv = s_ix[wv][l];
        int rank = 0;
        #pragma unroll 1
        for (int o = 0; o < 32; ++o) {
            float vo = s_sc[wv][o]; int io = s_ix[wv][o];
            rank += ((vo > v) || (vo == v && io < iv)) ? 1 : 0;
        }
        if (rank < 8) s_win[wv][rank] = iv;
    }
    __syncthreads();

    // ---- gather-mean of raw x rows; lane covers elems {2l, 2l+1} (fully coalesced/row) ----
    {
        int iw[8];
        #pragma unroll
        for (int w8 = 0; w8 < 8; ++w8) iw[w8] = s_win[wv][w8];
        const float* bb = xb + 2 * l;
        float2 v[8];
        #pragma unroll
        for (int w8 = 0; w8 < 8; ++w8)
            v[w8] = *(const float2*)(bb + (size_t)iw[w8] * D);
        float2 a2;
        a2.x = __fadd_rn(__fadd_rn(__fadd_rn(v[0].x, v[1].x), __fadd_rn(v[2].x, v[3].x)),
                         __fadd_rn(__fadd_rn(v[4].x, v[5].x), __fadd_rn(v[6].x, v[7].x)));
        a2.y = __fadd_rn(__fadd_rn(__fadd_rn(v[0].y, v[1].y), __fadd_rn(v[2].y, v[3].y)),
                         __fadd_rn(__fadd_rn(v[4].y, v[5].y), __fadd_rn(v[6].y, v[7].y)));
        a2.x *= 0.125f; a2.y *= 0.125f;
        *(float2*)(xagg + R * D + 2 * l) = a2;
    }
}

// ---------------- K3: h = x_agg @ W + b, LayerNorm -> hn (in-place over x_agg ws) ----------------
__global__ __launch_bounds__(256) void k_gemm1_ln(float* __restrict__ ws0,
                                                  const float* __restrict__ W,
                                                  const float* __restrict__ bvec,
                                                  const float* __restrict__ gamma,
                                                  const float* __restrict__ beta) {
    __shared__ float s_a[64 * 132];
    __shared__ float s_red[640];
    int t = threadIdx.x;
    size_t row0 = (size_t)blockIdx.x * 64;

    #pragma unroll
    for (int r = 0; r < 8; ++r) {
        int id = t + 256 * r;
        int row = id >> 5, c4 = (id & 31) << 2;
        *(float4*)&s_a[row * 132 + c4] = *(const float4*)(ws0 + (row0 + row) * D + c4);
    }
    __syncthreads();

    int mg = t >> 4, ng = t & 15;
    float acc[4][8];
    #pragma unroll
    for (int s = 0; s < 4; ++s)
        #pragma unroll
        for (int n = 0; n < 8; ++n) acc[s][n] = 0.0f;

    #pragma unroll 4
    for (int kc = 0; kc < 32; ++kc) {
        float4 a[4];
        #pragma unroll
        for (int s = 0; s < 4; ++s) a[s] = *(const float4*)&s_a[(mg + 16 * s) * 132 + kc * 4];
        #pragma unroll
        for (int i = 0; i < 4; ++i) {
            int k = kc * 4 + i;
            float4 bA = *(const float4*)(W + k * D + ng * 8);
            float4 bB = *(const float4*)(W + k * D + ng * 8 + 4);
            #pragma unroll
            for (int s = 0; s < 4; ++s) {
                float av = COMP(a[s], i);
                acc[s][0] = fmaf(av, bA.x, acc[s][0]);
                acc[s][1] = fmaf(av, bA.y, acc[s][1]);
                acc[s][2] = fmaf(av, bA.z, acc[s][2]);
                acc[s][3] = fmaf(av, bA.w, acc[s][3]);
                acc[s][4] = fmaf(av, bB.x, acc[s][4]);
                acc[s][5] = fmaf(av, bB.y, acc[s][5]);
                acc[s][6] = fmaf(av, bB.z, acc[s][6]);
                acc[s][7] = fmaf(av, bB.w, acc[s][7]);
            }
        }
    }
    __syncthreads();
    {
        float4 bA = *(const float4*)(bvec + ng * 8);
        float4 bB = *(const float4*)(bvec + ng * 8 + 4);
        #pragma unroll
        for (int s = 0; s < 4; ++s) {
            int row = mg + 16 * s;
            float4 h0 = make_float4(acc[s][0] + bA.x, acc[s][1] + bA.y,
                                    acc[s][2] + bA.z, acc[s][3] + bA.w);
            float4 h1 = make_float4(acc[s][4] + bB.x, acc[s][5] + bB.y,
                                    acc[s][6] + bB.z, acc[s][7] + bB.w);
            *(float4*)&s_a[row * 132 + ng * 8]     = h0;
            *(float4*)&s_a[row * 132 + ng * 8 + 4] = h1;
        }
    }
    __syncthreads();
    {
        int row = t & 63, q = t >> 6;
        float sm = 0.f, ssq = 0.f;
        #pragma unroll
        for (int c4 = 0; c4 < 8; ++c4) {
            float4 h = *(const float4*)&s_a[row * 132 + q * 32 + c4 * 4];
            sm += h.x + h.y + h.z + h.w;
            ssq = fmaf(h.x, h.x, ssq); ssq = fmaf(h.y, h.y, ssq);
            ssq = fmaf(h.z, h.z, ssq); ssq = fmaf(h.w, h.w, ssq);
        }
        s_red[row * 4 + q] = sm;
        s_red[256 + row * 4 + q] = ssq;
    }
    __syncthreads();
    if (t < 64) {
        float sm  = s_red[t * 4] + s_red[t * 4 + 1] + s_red[t * 4 + 2] + s_red[t * 4 + 3];
        float ssq = s_red[256 + t * 4] + s_red[256 + t * 4 + 1] +
                    s_red[256 + t * 4 + 2] + s_red[256 + t * 4 + 3];
        float mu  = sm * (1.0f / 128.0f);
        float var = ssq * (1.0f / 128.0f) - mu * mu;
        s_red[512 + t] = mu;
        s_red[576 + t] = 1.0f / sqrtf(var + 1e-5f);
    }
    __syncthreads();
    {
        int row = t & 63, q = t >> 6;
        float mu = s_red[512 + row], rs = s_red[576 + row];
        float* outp = ws0 + (row0 + row) * D + q * 32;
        #pragma unroll
        for (int c4 = 0; c4 < 8; ++c4) {
            float4 h  = *(const float4*)&s_a[row * 132 + q * 32 + c4 * 4];
            float4 g  = *(const float4*)(gamma + q * 32 + c4 * 4);
            float4 bt = *(const float4*)(beta  + q * 32 + c4 * 4);
            float4 o;
            o.x = fmaf((h.x - mu) * rs, g.x, bt.x);
            o.y = fmaf((h.y - mu) * rs, g.y, bt.y);
            o.z = fmaf((h.z - mu) * rs, g.z, bt.z);
            o.w = fmaf((h.w - mu) * rs, g.w, bt.w);
            *(float4*)(outp + c4 * 4) = o;
        }
    }
}

// ---------------- K4: out = relu(hn@W1+b1)@W2 + b2 ----------------
__global__ __launch_bounds__(256) void k_mlp(const float* __restrict__ hn,
                                             const float* __restrict__ W1,
                                             const float* __restrict__ b1,
                                             const float* __restrict__ W2,
                                             const float* __restrict__ b2,
                                             float* __restrict__ out) {
    __shared__ float s_h[32 * 132];
    __shared__ float s_t[32 * 132];
    int t = threadIdx.x;
    size_t row0 = (size_t)blockIdx.x * 32;

    #pragma unroll
    for (int r = 0; r < 4; ++r) {
        int id = t + 256 * r;
        int row = id >> 5, c4 = (id & 31) << 2;
        *(float4*)&s_h[row * 132 + c4] = *(const float4*)(hn + (row0 + row) * D + c4);
    }
    __syncthreads();

    int mg = t >> 5, ng = t & 31;
    float oacc[4][4];
    #pragma unroll
    for (int s = 0; s < 4; ++s)
        #pragma unroll
        for (int c = 0; c < 4; ++c) oacc[s][c] = 0.0f;

    for (int half = 0; half < 2; ++half) {
        float tacc[4][4];
        #pragma unroll
        for (int s = 0; s < 4; ++s)
            #pragma unroll
            for (int c = 0; c < 4; ++c) tacc[s][c] = 0.0f;
        #pragma unroll 4
        for (int kc = 0; kc < 32; ++kc) {
            float4 a[4];
            #pragma unroll
            for (int s = 0; s < 4; ++s) a[s] = *(const float4*)&s_h[(mg + 8 * s) * 132 + kc * 4];
            #pragma unroll
            for (int i = 0; i < 4; ++i) {
                float4 b = *(const float4*)(W1 + (kc * 4 + i) * 256 + half * 128 + ng * 4);
                #pragma unroll
                for (int s = 0; s < 4; ++s) {
                    float av = COMP(a[s], i);
                    tacc[s][0] = fmaf(av, b.x, tacc[s][0]);
                    tacc[s][1] = fmaf(av, b.y, tacc[s][1]);
                    tacc[s][2] = fmaf(av, b.z, tacc[s][2]);
                    tacc[s][3] = fmaf(av, b.w, tacc[s][3]);
                }
            }
        }
        float4 bb1 = *(const float4*)(b1 + half * 128 + ng * 4);
        #pragma unroll
        for (int s = 0; s < 4; ++s) {
            tacc[s][0] = fmaxf(tacc[s][0] + bb1.x, 0.0f);
            tacc[s][1] = fmaxf(tacc[s][1] + bb1.y, 0.0f);
            tacc[s][2] = fmaxf(tacc[s][2] + bb1.z, 0.0f);
            tacc[s][3] = fmaxf(tacc[s][3] + bb1.w, 0.0f);
        }
        __syncthreads();
        #pragma unroll
        for (int s = 0; s < 4; ++s)
            *(float4*)&s_t[(mg + 8 * s) * 132 + ng * 4] =
                make_float4(tacc[s][0], tacc[s][1], tacc[s][2], tacc[s][3]);
        __syncthreads();
        #pragma unroll 4
        for (int kc = 0; kc < 32; ++kc) {
            float4 a[4];
            #pragma unroll
            for (int s = 0; s < 4; ++s) a[s] = *(const float4*)&s_t[(mg + 8 * s) * 132 + kc * 4];
            #pragma unroll
            for (int i = 0; i < 4; ++i) {
                float4 b = *(const float4*)(W2 + (half * 128 + kc * 4 + i) * 128 + ng * 4);
                #pragma unroll
                for (int s = 0; s < 4; ++s) {
                    float av = COMP(a[s], i);
                    oacc[s][0] = fmaf(av, b.x, oacc[s][0]);
                    oacc[s][1] = fmaf(av, b.y, oacc[s][1]);
                    oacc[s][2] = fmaf(av, b.z, oacc[s][2]);
                    oacc[s][3] = fmaf(av, b.w, oacc[s][3]);
                }
            }
        }
    }
    float4 bb2 = *(const float4*)(b2 + ng * 4);
    #pragma unroll
    for (int s = 0; s < 4; ++s) {
        float4 o = make_float4(oacc[s][0] + bb2.x, oacc[s][1] + bb2.y,
                               oacc[s][2] + bb2.z, oacc[s][3] + bb2.w);
        *(float4*)(out + (row0 + mg + 8 * s) * D + ng * 4) = o;
    }
}

extern "C" void kernel_launch(void* const* d_in, const int* in_sizes, int n_in,
                              void* d_out, int out_size, void* d_ws, size_t ws_size,
                              hipStream_t stream) {
    const float* x     = (const float*)d_in[0];
    const float* W     = (const float*)d_in[1];
    const float* b     = (const float*)d_in[2];
    const float* W1    = (const float*)d_in[3];
    const float* b1    = (const float*)d_in[4];
    const float* W2    = (const float*)d_in[5];
    const float* b2    = (const float*)d_in[6];
    const float* gamma = (const float*)d_in[7];
    const float* beta  = (const float*)d_in[8];

    float* ws   = (float*)d_ws;
    float* xagg = ws;                                   // ROWS*D f32; becomes hn after K3
    float* xn   = ws + (size_t)ROWS * D;                // ROWS*D f32 (np-bit-exact xn)
    unsigned short* xnbf = (unsigned short*)(ws + 2 * (size_t)ROWS * D);      // ROWS*D bf16
    unsigned short* cand = (unsigned short*)(ws + 2 * (size_t)ROWS * D + (size_t)ROWS * D / 2);
                                                        // ROWS*32 u16 candidate indices

    hipLaunchKernelGGL(k_normalize,   dim3(ROWS / 64), dim3(256), 0, stream, x, xn, xnbf);
    hipLaunchKernelGGL(k_topk_cand,   dim3(4, BJ),     dim3(256), 0, stream, xnbf, cand);
    hipLaunchKernelGGL(k_rescore_agg, dim3(ROWS / 4),  dim3(256), 0, stream, x, xn, cand, xagg);
    hipLaunchKernelGGL(k_gemm1_ln,    dim3(ROWS / 64), dim3(256), 0, stream, xagg, W, b, gamma, beta);
    hipLaunchKernelGGL(k_mlp,         dim3(ROWS / 32), dim3(256), 0, stream, xagg, W1, b1, W2, b2,
                       (float*)d_out);
}